// Round 3
// baseline (903.499 us; speedup 1.0000x reference)
//
#include <hip/hip_runtime.h>

// GCN 2-layer via CSR gather (no float atomics).
// Algebra: out1 = dinv ⊙ ((A+I)@(dinv⊙x)) @ W1 + b1  (aggregate BEFORE transform)
//          h = relu(out1); y2 = dinv ⊙ (h@W2); out = relu(dinv ⊙ (A+I)-agg(y2) + b2)

constexpr int F0 = 5, F1 = 16, F2 = 4;
constexpr int SCAN_B = 256;   // threads per scan block
constexpr int SCAN_E = 1024;  // elements per scan block (4/thread)

__global__ void zero_counts(int* __restrict__ cnt, int n) {
    int i = blockIdx.x * blockDim.x + threadIdx.x;
    if (i < n) cnt[i] = 0;
}

__global__ void count_deg(const int* __restrict__ dst, int* __restrict__ cnt, int ne) {
    int e = blockIdx.x * blockDim.x + threadIdx.x;
    if (e < ne) atomicAdd(&cnt[dst[e]], 1);
}

// ---- 3-kernel exclusive scan of cnt[n] -> rowptr[n+1], plus wpos copy + dinv ----
__global__ void scan_block_sums(const int* __restrict__ cnt, int* __restrict__ bsums, int n) {
    __shared__ int red[SCAN_B];
    int t = threadIdx.x;
    int base = blockIdx.x * SCAN_E + t * 4;
    int s = 0;
#pragma unroll
    for (int k = 0; k < 4; k++) {
        int i = base + k;
        if (i < n) s += cnt[i];
    }
    red[t] = s;
    __syncthreads();
    for (int ofs = SCAN_B / 2; ofs > 0; ofs >>= 1) {
        if (t < ofs) red[t] += red[t + ofs];
        __syncthreads();
    }
    if (t == 0) bsums[blockIdx.x] = red[0];
}

__global__ void scan_bsums(int* __restrict__ bsums, int nb) {
    __shared__ int s[2048];
    for (int i = threadIdx.x; i < nb; i += blockDim.x) s[i] = bsums[i];
    __syncthreads();
    if (threadIdx.x == 0) {
        int run = 0;
        for (int b = 0; b < nb; b++) { int v = s[b]; s[b] = run; run += v; }
    }
    __syncthreads();
    for (int i = threadIdx.x; i < nb; i += blockDim.x) bsums[i] = s[i];
}

__global__ void scan_finalize(const int* __restrict__ cnt, const int* __restrict__ bsums,
                              int* __restrict__ rowptr, int* __restrict__ wpos,
                              float* __restrict__ dinv, int n, int ne) {
    __shared__ int tsum[SCAN_B];
    int b = blockIdx.x, t = threadIdx.x;
    int base = b * SCAN_E + t * 4;
    int v[4];
    int s = 0;
#pragma unroll
    for (int k = 0; k < 4; k++) {
        int i = base + k;
        v[k] = (i < n) ? cnt[i] : 0;
        s += v[k];
    }
    tsum[t] = s;
    __syncthreads();
    // inclusive Hillis-Steele scan of tsum
    for (int ofs = 1; ofs < SCAN_B; ofs <<= 1) {
        int y = (t >= ofs) ? tsum[t - ofs] : 0;
        __syncthreads();
        tsum[t] += y;
        __syncthreads();
    }
    int run = bsums[b] + tsum[t] - s;  // exclusive offset of this thread's first element
#pragma unroll
    for (int k = 0; k < 4; k++) {
        int i = base + k;
        if (i < n) {
            rowptr[i] = run;
            wpos[i] = run;
            dinv[i] = rsqrtf((float)(v[k] + 1));
            run += v[k];
        }
    }
    if (b == 0 && t == 0) rowptr[n] = ne;
}

__global__ void fill_csr(const int* __restrict__ src, const int* __restrict__ dst,
                         int* __restrict__ wpos, int* __restrict__ srcs, int ne) {
    int e = blockIdx.x * blockDim.x + threadIdx.x;
    if (e >= ne) return;
    int d = dst[e];
    int p = atomicAdd(&wpos[d], 1);
    srcs[p] = src[e];
}

// g1[i][0..4] = dinv[i] * x[i][0..4], rows padded to 8 floats (32B-aligned)
__global__ void make_g1(const float* __restrict__ x, const float* __restrict__ dinv,
                        float* __restrict__ g1, int n) {
    int i = blockIdx.x * blockDim.x + threadIdx.x;
    if (i >= n) return;
    float di = dinv[i];
#pragma unroll
    for (int j = 0; j < F0; j++) g1[i * 8 + j] = di * x[i * F0 + j];
}

// acc = g1[i] + sum_{s in N(i)} g1[s]; h = relu(dinv*(acc@W1)+b1); y2 = dinv*(h@W2)
__global__ void agg1_fused(const float* __restrict__ g1, const int* __restrict__ rowptr,
                           const int* __restrict__ srcs, const float* __restrict__ dinv,
                           const float* __restrict__ W1, const float* __restrict__ b1,
                           const float* __restrict__ W2, float* __restrict__ y2, int n) {
    __shared__ float w1[F0 * F1], bb1[F1], w2[F1 * F2];
    int t = threadIdx.x;
    if (t < F0 * F1) w1[t] = W1[t];
    if (t < F1) bb1[t] = b1[t];
    if (t < F1 * F2) w2[t] = W2[t];
    __syncthreads();
    int i = blockIdx.x * blockDim.x + t;
    if (i >= n) return;
    float4 a0 = *reinterpret_cast<const float4*>(g1 + (size_t)i * 8);
    float acc0 = a0.x, acc1 = a0.y, acc2 = a0.z, acc3 = a0.w, acc4 = g1[(size_t)i * 8 + 4];
    int e0 = rowptr[i], e1 = rowptr[i + 1];
    for (int e = e0; e < e1; e++) {
        int s = srcs[e];
        float4 b0 = *reinterpret_cast<const float4*>(g1 + (size_t)s * 8);
        acc0 += b0.x; acc1 += b0.y; acc2 += b0.z; acc3 += b0.w;
        acc4 += g1[(size_t)s * 8 + 4];
    }
    float di = dinv[i];
    float h[F1];
#pragma unroll
    for (int j = 0; j < F1; j++) {
        float v = acc0 * w1[0 * F1 + j] + acc1 * w1[1 * F1 + j] + acc2 * w1[2 * F1 + j] +
                  acc3 * w1[3 * F1 + j] + acc4 * w1[4 * F1 + j];
        v = di * v + bb1[j];
        h[j] = v > 0.f ? v : 0.f;
    }
    float4 o;
    float* op = &o.x;
#pragma unroll
    for (int j = 0; j < F2; j++) {
        float v = 0.f;
#pragma unroll
        for (int k = 0; k < F1; k++) v += h[k] * w2[k * F2 + j];
        op[j] = di * v;
    }
    *reinterpret_cast<float4*>(y2 + (size_t)i * 4) = o;
}

// acc = y2[i] + sum y2[s]; out = relu(dinv*acc + b2)
__global__ void agg2_finish(const float* __restrict__ y2, const int* __restrict__ rowptr,
                            const int* __restrict__ srcs, const float* __restrict__ dinv,
                            const float* __restrict__ b2, float* __restrict__ out, int n) {
    int i = blockIdx.x * blockDim.x + threadIdx.x;
    if (i >= n) return;
    float4 acc = *reinterpret_cast<const float4*>(y2 + (size_t)i * 4);
    int e0 = rowptr[i], e1 = rowptr[i + 1];
    for (int e = e0; e < e1; e++) {
        int s = srcs[e];
        float4 v = *reinterpret_cast<const float4*>(y2 + (size_t)s * 4);
        acc.x += v.x; acc.y += v.y; acc.z += v.z; acc.w += v.w;
    }
    float di = dinv[i];
    float4 r;
    r.x = fmaxf(di * acc.x + b2[0], 0.f);
    r.y = fmaxf(di * acc.y + b2[1], 0.f);
    r.z = fmaxf(di * acc.z + b2[2], 0.f);
    r.w = fmaxf(di * acc.w + b2[3], 0.f);
    *reinterpret_cast<float4*>(out + (size_t)i * 4) = r;
}

extern "C" void kernel_launch(void* const* d_in, const int* in_sizes, int n_in,
                              void* d_out, int out_size, void* d_ws, size_t ws_size,
                              hipStream_t stream) {
    const float* x  = (const float*)d_in[0];
    const int*   ei = (const int*)d_in[1];   // [2, E]
    const float* W1 = (const float*)d_in[2];
    const float* b1 = (const float*)d_in[3];
    const float* W2 = (const float*)d_in[4];
    const float* b2 = (const float*)d_in[5];
    float* out = (float*)d_out;

    const int n  = in_sizes[0] / F0;   // 250000
    const int ne = in_sizes[1] / 2;    // 5000000
    const int* src = ei;
    const int* dst = ei + ne;

    // workspace layout, 256B-aligned; total ~36 MB (previous 41 MB layout fit)
    char* ws = (char*)d_ws;
    size_t off = 0;
    auto alloc = [&](size_t bytes) { void* p = ws + off; off += (bytes + 255) & ~255ull; return p; };
    int*   cnt    = (int*)alloc((size_t)n * 4);
    int*   rowptr = (int*)alloc((size_t)(n + 1) * 4);
    int*   wpos   = (int*)alloc((size_t)n * 4);
    float* dinv   = (float*)alloc((size_t)n * 4);
    int*   bsums  = (int*)alloc(4096);
    int*   srcs   = (int*)alloc((size_t)ne * 4);       // 20 MB
    float* g1     = (float*)alloc((size_t)n * 8 * 4);  // 8 MB
    float* y2     = (float*)alloc((size_t)n * 4 * 4);  // 4 MB

    const int B = 256;
    const int nb_scan = (n + SCAN_E - 1) / SCAN_E;  // 245

    zero_counts<<<(n + B - 1) / B, B, 0, stream>>>(cnt, n);
    count_deg<<<(ne + B - 1) / B, B, 0, stream>>>(dst, cnt, ne);
    scan_block_sums<<<nb_scan, SCAN_B, 0, stream>>>(cnt, bsums, n);
    scan_bsums<<<1, 256, 0, stream>>>(bsums, nb_scan);
    scan_finalize<<<nb_scan, SCAN_B, 0, stream>>>(cnt, bsums, rowptr, wpos, dinv, n, ne);
    fill_csr<<<(ne + B - 1) / B, B, 0, stream>>>(src, dst, wpos, srcs, ne);

    make_g1<<<(n + B - 1) / B, B, 0, stream>>>(x, dinv, g1, n);
    agg1_fused<<<(n + B - 1) / B, B, 0, stream>>>(g1, rowptr, srcs, dinv, W1, b1, W2, y2, n);
    agg2_finish<<<(n + B - 1) / B, B, 0, stream>>>(y2, rowptr, srcs, dinv, b2, out, n);
}